// Round 12
// baseline (1128.351 us; speedup 1.0000x reference)
//
#include <hip/hip_runtime.h>

typedef unsigned short ushort_t;
typedef unsigned int uint_t;
typedef unsigned long long ull_t;
typedef short v8s __attribute__((ext_vector_type(8)));
typedef float v4f __attribute__((ext_vector_type(4)));

__device__ __forceinline__ float b2f(ushort_t u) {
    uint_t x = ((uint_t)u) << 16;
    float f;
    __builtin_memcpy(&f, &x, 4);
    return f;
}
__device__ __forceinline__ ushort_t f2b(float f) {
    uint_t x;
    __builtin_memcpy(&x, &f, 4);
    uint_t r = (x + 0x7FFFu + ((x >> 16) & 1u)) >> 16;
    return (ushort_t)r;
}

// ---------------------------------------------------------------------------
// k_prep: merged k_setup + k_pre (mutually independent work, one launch).
// blocks 0..63      : zero 8-slot h ring
// blocks 64..1411   : weight fp32->bf16 conversion (float4 -> packed 8B)
// blocks 1412..1923 : k_pre (delta/mask/value/gamma_x precompute)
// ---------------------------------------------------------------------------
__global__ __launch_bounds__(256) void k_prep(
    const float* __restrict__ Wih, const float* __restrict__ Whh,
    const float* __restrict__ Wgh, const float* __restrict__ Whist,
    const float* __restrict__ Wfeat,
    ushort_t* __restrict__ Wih_b, ushort_t* __restrict__ Whh_b,
    ushort_t* __restrict__ Wgh_b, ushort_t* __restrict__ Whist_b,
    ushort_t* __restrict__ Wfeat_b, ull_t* __restrict__ hbufs,
    const float* __restrict__ data, const float* __restrict__ Wgx,
    const float* __restrict__ bgx,
    ushort_t* __restrict__ values, ushort_t* __restrict__ masks,
    ushort_t* __restrict__ deltas, ushort_t* __restrict__ gammax) {
    __shared__ int lastl[32][9];
    int bid = blockIdx.x, tid = threadIdx.x;
    if (bid < 64) {   // zero 8 slots x 131072 u16 = 262144 ull
        ull_t* p = hbufs + (size_t)bid * 4096 + tid;
#pragma unroll
        for (int i = 0; i < 16; ++i) p[i * 256] = 0;
        return;
    }
    if (bid < 1412) {  // weight conversion
        bid -= 64;
        const float* src; ushort_t* dst;
        if (bid < 256)       { src = Wih;   dst = Wih_b;   }
        else if (bid < 1280) { bid -= 256;  src = Whh;   dst = Whh_b;   }
        else if (bid < 1312) { bid -= 1280; src = Wgh;   dst = Wgh_b;   }
        else if (bid < 1344) { bid -= 1312; src = Whist; dst = Whist_b; }
        else                 { bid -= 1344; src = Wfeat; dst = Wfeat_b; }
        int e0 = bid * 1024 + tid * 4;
        float4 f = *(const float4*)(src + e0);
        ull_t packed = (ull_t)f2b(f.x) | ((ull_t)f2b(f.y) << 16) |
                       ((ull_t)f2b(f.z) << 32) | ((ull_t)f2b(f.w) << 48);
        *(ull_t*)(dst + e0) = packed;
        return;
    }
    // ---- k_pre part: 512 blocks; 32 (b,c) pairs x 8 threads over T chunks.
    // delta[t] = t - L(t), L(t) = last t' in [1,t-1] with m[t']=1 (else 0).
    bid -= 1412;
    int j = tid >> 5, p = tid & 31;
    int pid = bid * 32 + p;             // 0..16383
    int b = pid >> 6, c = pid & 63;
    float wd = Wgx[c * 64 + c], bg = bgx[c];
    int t0 = j * 32;
    const float* dp = data + (size_t)b * 16384 + c;
    float v[32]; uint_t bits = 0;
#pragma unroll
    for (int s = 0; s < 32; ++s) {
        float x = dp[(t0 + s) * 64];
        bool obs = (x == x);
        v[s] = obs ? x : 0.f;
        bits |= obs ? (1u << s) : 0u;
    }
    uint_t vb = bits;
    if (j == 0) vb &= ~1u;              // t=0 never counts as observation
    int lastloc = 0;
    if (vb) lastloc = t0 + (31 - __clz(vb));
    lastl[p][j] = lastloc;
    __syncthreads();
    int L = 0;
    for (int jj = 0; jj < j; ++jj) L = max(L, lastl[p][jj]);
#pragma unroll
    for (int s = 0; s < 32; ++s) {
        int t = t0 + s;
        float m = ((bits >> s) & 1) ? 1.f : 0.f;
        float d = (t == 0) ? 0.f : (float)(t - L);
        float sg = d * wd + bg;
        float gx = (sg > 0.f) ? __expf(-sg) : 1.f;
        size_t o = (size_t)t * 16384 + pid;
        values[o] = f2b(v[s]); masks[o] = f2b(m);
        deltas[o] = f2b(d);    gammax[o] = f2b(gx);
        if (((bits >> s) & 1) && t >= 1) L = t;
    }
}

// ---------------------------------------------------------------------------
// k_alpha: MFMA GEMM. out[65536 x 64] = [gammax|masks][65536 x 128] @ Wcomb^T.
// 1024 blocks x 64 rows (4 waves x 16 rows); 16 MFMAs/wave.
// ---------------------------------------------------------------------------
__global__ __launch_bounds__(256) void k_alpha(
    const ushort_t* __restrict__ gammax, const ushort_t* __restrict__ masks,
    const float* __restrict__ Wcomb, const float* __restrict__ bcomb,
    ushort_t* __restrict__ alpha) {
    __shared__ __attribute__((aligned(16))) ushort_t wl[64 * 136];
    __shared__ __attribute__((aligned(16))) ushort_t al[64 * 136];
    int tid = threadIdx.x;
    for (int idx = tid; idx < 8192; idx += 256) {
        int r = idx >> 7, kcol = idx & 127;
        wl[r * 136 + kcol] = f2b(Wcomb[idx]);
    }
    int tb0 = blockIdx.x * 64;
    for (int idx = tid; idx < 8192; idx += 256) {
        int r = idx >> 7, kcol = idx & 127;
        al[r * 136 + kcol] = (kcol < 64)
            ? gammax[(size_t)(tb0 + r) * 64 + kcol]
            : masks[(size_t)(tb0 + r) * 64 + (kcol - 64)];
    }
    __syncthreads();
    int w = tid >> 6, lane = tid & 63, l15 = lane & 15, quad = lane >> 4;
    v4f acc[4] = {};
#pragma unroll
    for (int kt = 0; kt < 4; ++kt) {
        v8s a = *(const v8s*)(al + (w * 16 + l15) * 136 + kt * 32 + quad * 8);
#pragma unroll
        for (int nt = 0; nt < 4; ++nt) {
            v8s bfr = *(const v8s*)(wl + (nt * 16 + l15) * 136 + kt * 32 + quad * 8);
            acc[nt] = __builtin_amdgcn_mfma_f32_16x16x32_bf16(a, bfr, acc[nt], 0, 0, 0);
        }
    }
#pragma unroll
    for (int nt = 0; nt < 4; ++nt) {
        int col = nt * 16 + l15;
        float bc = bcomb[col];
#pragma unroll
        for (int j = 0; j < 4; ++j) {
            int row = w * 16 + quad * 4 + j;
            alpha[(size_t)(tb0 + row) * 64 + col] = f2b(acc[nt][j] + bc);
        }
    }
}

// ---------------------------------------------------------------------------
// k_run: persistent, 8-slot h ring, data-polling sync (bf16+1 encoding),
// producer pre-zero of slot (t+4)%8 (safe: intra-group drift <= 1 step and
// every __syncthreads drains vmcnt, so zeros are globally visible >=2 steps
// before any producer can rewrite or any consumer can poll that slot).
// Round-12 SINGLE change vs verified ~810us build: poll loads are issued
// FIRST in the step (oldest in the VMEM queue), P prefetch loads after,
// with sched_barrier(0) pinning the order. The compiler's counted waitcnt
// at the hv check then waits only on the 8 poll loads (vmcnt(12)), not on
// the 12 P loads -- consumer detect latency decouples from the prefetch
// drain on the critical consumer-behind-producer chain. No protocol,
// store, or layout changes.
// ---------------------------------------------------------------------------
__global__ __launch_bounds__(256, 1) void k_run(
    const ushort_t* __restrict__ values, const ushort_t* __restrict__ masks,
    const ushort_t* __restrict__ deltas, const ushort_t* __restrict__ alpha,
    const ushort_t* __restrict__ Wih, const ushort_t* __restrict__ Whh,
    const float* __restrict__ bih, const float* __restrict__ bhh,
    const ushort_t* __restrict__ Wgh, const float* __restrict__ bgh,
    const ushort_t* __restrict__ Whist, const float* __restrict__ bhist,
    const ushort_t* __restrict__ Wfeat, const float* __restrict__ bfeat,
    ushort_t* __restrict__ hbufs, float* __restrict__ out) {
    __shared__ __attribute__((aligned(16))) ushort_t hlds[16 * 520];
    __shared__ __attribute__((aligned(16))) ushort_t inplds[16 * 136];
    __shared__ __attribute__((aligned(16))) ushort_t xclds[16 * 72];
    __shared__ __attribute__((aligned(16))) ushort_t d1b[16 * 72];
    __shared__ __attribute__((aligned(16))) float gl[4 * 16 * 36];
    __shared__ __attribute__((aligned(16))) float gam[16 * 36];

    int tid = threadIdx.x;
    int w = tid >> 6;
    int lane = tid & 63;
    int l15 = lane & 15, quad = lane >> 4;
    int wg = blockIdx.x;
    int rb = wg & 15, cb = wg >> 4;
    int b0 = rb * 16;

    // ---- persistent weight fragments ----
    v8s whhF[2][16], wihF[2][4], whisF[16], wfF[2], wghF[2] = {};
    float biasv[2];
#pragma unroll
    for (int nt2 = 0; nt2 < 2; ++nt2) {
        int hc = cb * 32 + nt2 * 16 + l15;
        int rW = w * 512 + hc;
        const ushort_t* whrow = Whh + (size_t)rW * 512;
        const ushort_t* wirow = Wih + (size_t)rW * 128;
#pragma unroll
        for (int kt = 0; kt < 16; ++kt)
            whhF[nt2][kt] = *(const v8s*)(whrow + kt * 32 + quad * 8);
#pragma unroll
        for (int kt = 0; kt < 4; ++kt)
            wihF[nt2][kt] = *(const v8s*)(wirow + kt * 32 + quad * 8);
        biasv[nt2] = bih[rW] + bhh[rW];
    }
    int colC = w * 16 + l15;
    {
        const ushort_t* hrow = Whist + (size_t)colC * 512;
#pragma unroll
        for (int kt = 0; kt < 16; ++kt)
            whisF[kt] = *(const v8s*)(hrow + kt * 32 + quad * 8);
        const ushort_t* frow = Wfeat + colC * 64;
#pragma unroll
        for (int kt = 0; kt < 2; ++kt) {
            int k0 = kt * 32 + quad * 8;
            v8s bb = *(const v8s*)(frow + k0);
#pragma unroll
            for (int j = 0; j < 8; ++j)
                if (k0 + j == colC) bb[j] = 0;   // zero diagonal
            wfF[kt] = bb;
        }
    }
    float bghv = 0.f;
    if (w < 2) {
        int gcol = cb * 32 + w * 16 + l15;
        const ushort_t* grow = Wgh + gcol * 64;
#pragma unroll
        for (int kt = 0; kt < 2; ++kt)
            wghF[kt] = *(const v8s*)(grow + kt * 32 + quad * 8);
        bghv = bgh[gcol];
    }
    float bhistv = bhist[colC];
    float bfeatv = bfeat[colC];

    int sf_row = tid >> 3, sf_c4 = (tid & 7) * 4;   // pre-zero addressing
    // SF-spread addressing: pair pr = tid>>1 owns (row, 4-col unit); this
    // thread handles cols c4 + sub*2 + {0,1}.
    int pr = tid >> 1;
    int sp_row = pr >> 3, sp_c4 = (pr & 7) * 4, sub = tid & 1;
    float c_reg2[2] = {0.f, 0.f};

    for (int t = 0; t < 256; ++t) {
        // ---- S0a: issue poll loads FIRST (oldest in the VMEM queue) ----
        const ull_t* hp[8];
        ull_t hv[8];
        if (t > 0) {
            const ushort_t* hb = hbufs + (size_t)(t & 7) * 131072;
#pragma unroll
            for (int i = 0; i < 8; ++i) {
                int c = tid + 256 * i;
                int row = c >> 7, c4 = (c & 127) * 4;
                hp[i] = (const ull_t*)(hb + (b0 + row) * 512 + c4);
                hv[i] = __hip_atomic_load(hp[i], __ATOMIC_RELAXED,
                                          __HIP_MEMORY_SCOPE_AGENT);
            }
        }
        __builtin_amdgcn_sched_barrier(0);

        // ---- P: prefetch (issued after polls; drains underneath) ----
        float v4r[4], m4r[4], a4r[4];
#pragma unroll
        for (int r = 0; r < 4; ++r) {
            int row = quad * 4 + r;
            size_t g = (size_t)t * 16384 + (b0 + row) * 64 + colC;
            v4r[r] = b2f(values[g]);
            m4r[r] = b2f(masks[g]);
            a4r[r] = b2f(alpha[g]);
        }
        v8s mreg = {}, dreg = {};
        if (tid < 128) {
            int row = tid >> 3, c8 = (tid & 7) * 8;
            int tn = (t < 255) ? t + 1 : 255;
            mreg = *(const v8s*)(masks + (size_t)t * 16384 + (b0 + row) * 64 + c8);
            dreg = *(const v8s*)(deltas + (size_t)tn * 16384 + (b0 + row) * 64 + c8);
        }
        __builtin_amdgcn_sched_barrier(0);

        // ---- S0b: check/spin h(t); decode; stage LDS ----
        if (t == 0) {
            v8s z = {0, 0, 0, 0, 0, 0, 0, 0};
            for (int idx = tid; idx < 1040; idx += 256) ((v8s*)hlds)[idx] = z;
        } else {
            int guard = 0;
            while (true) {
                bool any = false;
#pragma unroll
                for (int i = 0; i < 8; ++i) any |= (hv[i] == 0);
                if (!any || ++guard > (1 << 20)) break;
                __builtin_amdgcn_s_sleep(1);
#pragma unroll
                for (int i = 0; i < 8; ++i)
                    if (hv[i] == 0)
                        hv[i] = __hip_atomic_load(hp[i], __ATOMIC_RELAXED,
                                                  __HIP_MEMORY_SCOPE_AGENT);
            }
#pragma unroll
            for (int i = 0; i < 8; ++i) {
                int c = tid + 256 * i;
                int row = c >> 7, c4 = (c & 127) * 4;
                *(ull_t*)(hlds + row * 520 + c4) =
                    hv[i] - 0x0001000100010001ULL;   // decode bf16+1
            }
        }
        if (tid < 128) {
            int row = tid >> 3, c8 = (tid & 7) * 8;
            *(v8s*)(inplds + row * 136 + 64 + c8) = mreg;
            *(v8s*)(d1b + row * 72 + c8) = dreg;
        }
        __syncthreads();

        // ---- SA: xh + 2 gate chains share A-frags; m-half of Wih folded in;
        //      gamma tile; xc epilogue ----
        v4f accx = {0.f, 0.f, 0.f, 0.f};
        v4f accg0 = {0.f, 0.f, 0.f, 0.f}, accg1 = {0.f, 0.f, 0.f, 0.f};
#pragma unroll
        for (int kt = 0; kt < 16; ++kt) {
            v8s a = *(const v8s*)(hlds + l15 * 520 + kt * 32 + quad * 8);
            accx = __builtin_amdgcn_mfma_f32_16x16x32_bf16(a, whisF[kt], accx, 0, 0, 0);
            accg0 = __builtin_amdgcn_mfma_f32_16x16x32_bf16(a, whhF[0][kt], accg0, 0, 0, 0);
            accg1 = __builtin_amdgcn_mfma_f32_16x16x32_bf16(a, whhF[1][kt], accg1, 0, 0, 0);
        }
        // m-half of the gate GEMM (inplds cols 64..127, staged at S0) --
        // does NOT depend on SC; removed from the post-SC critical path.
#pragma unroll
        for (int kt = 2; kt < 4; ++kt) {
            v8s a = *(const v8s*)(inplds + l15 * 136 + kt * 32 + quad * 8);
            accg0 = __builtin_amdgcn_mfma_f32_16x16x32_bf16(a, wihF[0][kt], accg0, 0, 0, 0);
            accg1 = __builtin_amdgcn_mfma_f32_16x16x32_bf16(a, wihF[1][kt], accg1, 0, 0, 0);
        }
        if (w < 2) {
            v4f acc = {0.f, 0.f, 0.f, 0.f};
#pragma unroll
            for (int kt = 0; kt < 2; ++kt) {
                v8s a = *(const v8s*)(d1b + l15 * 72 + kt * 32 + quad * 8);
                acc = __builtin_amdgcn_mfma_f32_16x16x32_bf16(a, wghF[kt], acc, 0, 0, 0);
            }
#pragma unroll
            for (int r = 0; r < 4; ++r) {
                float s = acc[r] + bghv;
                gam[(quad * 4 + r) * 36 + w * 16 + l15] = (s > 0.f) ? __expf(-s) : 1.f;
            }
        }
        float xh4[4];
#pragma unroll
        for (int r = 0; r < 4; ++r) {
            float xh = accx[r] + bhistv;
            float xc = m4r[r] * v4r[r] + (1.f - m4r[r]) * xh;
            xclds[(quad * 4 + r) * 72 + colC] = f2b(xc);
            xh4[r] = xh;
        }
        __syncthreads();

        // ---- SC: z_h MFMA; c_h/c_c epilogue in C-layout; cc kept in regs ----
        float cc4[4];
        {
            v4f accz = {0.f, 0.f, 0.f, 0.f};
#pragma unroll
            for (int kt = 0; kt < 2; ++kt) {
                v8s a = *(const v8s*)(xclds + l15 * 72 + kt * 32 + quad * 8);
                accz = __builtin_amdgcn_mfma_f32_16x16x32_bf16(a, wfF[kt], accz, 0, 0, 0);
            }
#pragma unroll
            for (int r = 0; r < 4; ++r) {
                float zh = accz[r] + bfeatv;
                float ch = a4r[r] * zh + (1.f - a4r[r]) * xh4[r];
                float cc = m4r[r] * v4r[r] + (1.f - m4r[r]) * ch;
                int row = quad * 4 + r;
                inplds[row * 136 + colC] = f2b(cc);
                cc4[r] = cc;   // out-store deferred to step tail
            }
        }
        __syncthreads();

        // ---- SE: gates Wih cc-half only (kt=0,1); gate planes ----
#pragma unroll
        for (int nt2 = 0; nt2 < 2; ++nt2) {
            v4f acc = (nt2 == 0) ? accg0 : accg1;
#pragma unroll
            for (int kt = 0; kt < 2; ++kt) {
                v8s a = *(const v8s*)(inplds + l15 * 136 + kt * 32 + quad * 8);
                acc = __builtin_amdgcn_mfma_f32_16x16x32_bf16(a, wihF[nt2][kt], acc, 0, 0, 0);
            }
#pragma unroll
            for (int r = 0; r < 4; ++r)
                gl[w * 576 + (quad * 4 + r) * 36 + nt2 * 16 + l15] = acc[r] + biasv[nt2];
        }
        __syncthreads();

        // ---- SF: LSTM spread over ALL 256 threads (2 cols each);
        //      shfl-merge to the identical 8B encoded store ----
        {
            uint_t myu = 0;
#pragma unroll
            for (int jj = 0; jj < 2; ++jj) {
                int hcl = sp_c4 + sub * 2 + jj;
                float gi = gl[0 * 576 + sp_row * 36 + hcl];
                float gf = gl[1 * 576 + sp_row * 36 + hcl];
                float gg = gl[2 * 576 + sp_row * 36 + hcl];
                float go = gl[3 * 576 + sp_row * 36 + hcl];
                float si = 1.f / (1.f + __expf(-gi));
                float sf = 1.f / (1.f + __expf(-gf));
                float tg = 1.f - 2.f / (__expf(2.f * gg) + 1.f);
                float so = 1.f / (1.f + __expf(-go));
                float cn = sf * c_reg2[jj] + si * tg;
                c_reg2[jj] = cn;
                float hn = so * (1.f - 2.f / (__expf(2.f * cn) + 1.f));
                float g = gam[sp_row * 36 + hcl];
                myu |= (uint_t)(ushort_t)(f2b(hn * g) + 1) << (16 * jj);
            }
            uint_t pu = __shfl_xor(myu, 1);
            if (sub == 0 && t < 255) {
                ull_t outv = (ull_t)myu | ((ull_t)pu << 32);
                ushort_t* hnx = hbufs + (size_t)((t + 1) & 7) * 131072;
                size_t myoff = (size_t)(b0 + sp_row) * 512 + cb * 32 + sp_c4;
                __hip_atomic_store((ull_t*)(hnx + myoff), outv,
                                   __ATOMIC_RELAXED, __HIP_MEMORY_SCOPE_AGENT);
            }
        }
        // ---- pre-zero slot (t+4)%8 (8B per thread, tid<128; unchanged) ----
        if (tid < 128 && t + 4 < 256) {
            ushort_t* hz = hbufs + (size_t)((t + 4) & 7) * 131072;
            size_t myoff = (size_t)(b0 + sf_row) * 512 + cb * 32 + sf_c4;
            __hip_atomic_store((ull_t*)(hz + myoff), 0ULL,
                               __ATOMIC_RELAXED, __HIP_MEMORY_SCOPE_AGENT);
        }
        // ---- deferred out store (issued after h publish; drains with it) ----
        if (cb == 0) {
#pragma unroll
            for (int r = 0; r < 4; ++r) {
                int row = quad * 4 + r;
                out[(size_t)(b0 + row) * 16384 + t * 64 + colC] = cc4[r];
            }
        }
        __syncthreads();   // drains vmcnt: protects LDS reuse + publishes h/zeros
    }
}

extern "C" void kernel_launch(void* const* d_in, const int* in_sizes, int n_in,
                              void* d_out, int out_size, void* d_ws, size_t ws_size,
                              hipStream_t stream) {
    const float* data  = (const float*)d_in[0];
    const float* Wih   = (const float*)d_in[1];
    const float* Whh   = (const float*)d_in[2];
    const float* bih   = (const float*)d_in[3];
    const float* bhh   = (const float*)d_in[4];
    const float* Wgh   = (const float*)d_in[5];
    const float* bgh   = (const float*)d_in[6];
    const float* Wgx   = (const float*)d_in[7];
    const float* bgx   = (const float*)d_in[8];
    const float* Whist = (const float*)d_in[9];
    const float* bhist = (const float*)d_in[10];
    const float* Wfeat = (const float*)d_in[11];
    const float* bfeat = (const float*)d_in[12];
    const float* Wcomb = (const float*)d_in[13];
    const float* bcomb = (const float*)d_in[14];
    float* out = (float*)d_out;

    char* ws = (char*)d_ws;
    const size_t NTBC = 256UL * 256 * 64;
    ushort_t* valuesb = (ushort_t*)ws; ws += NTBC * 2;
    ushort_t* masksp  = (ushort_t*)ws; ws += NTBC * 2;
    ushort_t* deltasp = (ushort_t*)ws; ws += NTBC * 2;
    ushort_t* gammax  = (ushort_t*)ws; ws += NTBC * 2;
    ushort_t* alphap  = (ushort_t*)ws; ws += NTBC * 2;
    ushort_t* Wih_b   = (ushort_t*)ws; ws += 2048UL * 128 * 2;
    ushort_t* Whh_b   = (ushort_t*)ws; ws += 2048UL * 512 * 2;
    ushort_t* Wgh_b   = (ushort_t*)ws; ws += 512UL * 64 * 2;
    ushort_t* Whist_b = (ushort_t*)ws; ws += 64UL * 512 * 2;
    ushort_t* Wfeat_b = (ushort_t*)ws; ws += 64UL * 64 * 2;
    ushort_t* hbufs   = (ushort_t*)ws; ws += 8UL * 131072 * 2;  // 2 MB ring
    // total ~44.6 MiB

    k_prep<<<1924, 256, 0, stream>>>(Wih, Whh, Wgh, Whist, Wfeat,
                                     Wih_b, Whh_b, Wgh_b, Whist_b, Wfeat_b,
                                     (ull_t*)hbufs,
                                     data, Wgx, bgx,
                                     valuesb, masksp, deltasp, gammax);
    k_alpha<<<1024, 256, 0, stream>>>(gammax, masksp, Wcomb, bcomb, alphap);
    k_run<<<256, 256, 0, stream>>>(valuesb, masksp, deltasp, alphap,
                                   Wih_b, Whh_b, bih, bhh,
                                   Wgh_b, bgh, Whist_b, bhist,
                                   Wfeat_b, bfeat, hbufs, out);
}

// Round 14
// 863.703 us; speedup vs baseline: 1.3064x; 1.3064x over previous
//
#include <hip/hip_runtime.h>

typedef unsigned short ushort_t;
typedef unsigned int uint_t;
typedef unsigned long long ull_t;
typedef short v8s __attribute__((ext_vector_type(8)));
typedef float v4f __attribute__((ext_vector_type(4)));

__device__ __forceinline__ float b2f(ushort_t u) {
    uint_t x = ((uint_t)u) << 16;
    float f;
    __builtin_memcpy(&f, &x, 4);
    return f;
}
__device__ __forceinline__ ushort_t f2b(float f) {
    uint_t x;
    __builtin_memcpy(&x, &f, 4);
    uint_t r = (x + 0x7FFFu + ((x >> 16) & 1u)) >> 16;
    return (ushort_t)r;
}

// ---------------------------------------------------------------------------
// k_prep: merged k_setup + k_pre (mutually independent work, one launch).
// blocks 0..63      : zero 8-slot h ring
// blocks 64..1411   : weight fp32->bf16 conversion (float4 -> packed 8B)
// blocks 1412..1923 : k_pre (delta/mask/value/gamma_x precompute)
// ---------------------------------------------------------------------------
__global__ __launch_bounds__(256) void k_prep(
    const float* __restrict__ Wih, const float* __restrict__ Whh,
    const float* __restrict__ Wgh, const float* __restrict__ Whist,
    const float* __restrict__ Wfeat,
    ushort_t* __restrict__ Wih_b, ushort_t* __restrict__ Whh_b,
    ushort_t* __restrict__ Wgh_b, ushort_t* __restrict__ Whist_b,
    ushort_t* __restrict__ Wfeat_b, ull_t* __restrict__ hbufs,
    const float* __restrict__ data, const float* __restrict__ Wgx,
    const float* __restrict__ bgx,
    ushort_t* __restrict__ values, ushort_t* __restrict__ masks,
    ushort_t* __restrict__ deltas, ushort_t* __restrict__ gammax) {
    __shared__ int lastl[32][9];
    int bid = blockIdx.x, tid = threadIdx.x;
    if (bid < 64) {   // zero 8 slots x 131072 u16 = 262144 ull
        ull_t* p = hbufs + (size_t)bid * 4096 + tid;
#pragma unroll
        for (int i = 0; i < 16; ++i) p[i * 256] = 0;
        return;
    }
    if (bid < 1412) {  // weight conversion
        bid -= 64;
        const float* src; ushort_t* dst;
        if (bid < 256)       { src = Wih;   dst = Wih_b;   }
        else if (bid < 1280) { bid -= 256;  src = Whh;   dst = Whh_b;   }
        else if (bid < 1312) { bid -= 1280; src = Wgh;   dst = Wgh_b;   }
        else if (bid < 1344) { bid -= 1312; src = Whist; dst = Whist_b; }
        else                 { bid -= 1344; src = Wfeat; dst = Wfeat_b; }
        int e0 = bid * 1024 + tid * 4;
        float4 f = *(const float4*)(src + e0);
        ull_t packed = (ull_t)f2b(f.x) | ((ull_t)f2b(f.y) << 16) |
                       ((ull_t)f2b(f.z) << 32) | ((ull_t)f2b(f.w) << 48);
        *(ull_t*)(dst + e0) = packed;
        return;
    }
    // ---- k_pre part: 512 blocks; 32 (b,c) pairs x 8 threads over T chunks.
    // delta[t] = t - L(t), L(t) = last t' in [1,t-1] with m[t']=1 (else 0).
    bid -= 1412;
    int j = tid >> 5, p = tid & 31;
    int pid = bid * 32 + p;             // 0..16383
    int b = pid >> 6, c = pid & 63;
    float wd = Wgx[c * 64 + c], bg = bgx[c];
    int t0 = j * 32;
    const float* dp = data + (size_t)b * 16384 + c;
    float v[32]; uint_t bits = 0;
#pragma unroll
    for (int s = 0; s < 32; ++s) {
        float x = dp[(t0 + s) * 64];
        bool obs = (x == x);
        v[s] = obs ? x : 0.f;
        bits |= obs ? (1u << s) : 0u;
    }
    uint_t vb = bits;
    if (j == 0) vb &= ~1u;              // t=0 never counts as observation
    int lastloc = 0;
    if (vb) lastloc = t0 + (31 - __clz(vb));
    lastl[p][j] = lastloc;
    __syncthreads();
    int L = 0;
    for (int jj = 0; jj < j; ++jj) L = max(L, lastl[p][jj]);
#pragma unroll
    for (int s = 0; s < 32; ++s) {
        int t = t0 + s;
        float m = ((bits >> s) & 1) ? 1.f : 0.f;
        float d = (t == 0) ? 0.f : (float)(t - L);
        float sg = d * wd + bg;
        float gx = (sg > 0.f) ? __expf(-sg) : 1.f;
        size_t o = (size_t)t * 16384 + pid;
        values[o] = f2b(v[s]); masks[o] = f2b(m);
        deltas[o] = f2b(d);    gammax[o] = f2b(gx);
        if (((bits >> s) & 1) && t >= 1) L = t;
    }
}

// ---------------------------------------------------------------------------
// k_alpha: MFMA GEMM. out[65536 x 64] = [gammax|masks][65536 x 128] @ Wcomb^T.
// 1024 blocks x 64 rows (4 waves x 16 rows); 16 MFMAs/wave.
// ---------------------------------------------------------------------------
__global__ __launch_bounds__(256) void k_alpha(
    const ushort_t* __restrict__ gammax, const ushort_t* __restrict__ masks,
    const float* __restrict__ Wcomb, const float* __restrict__ bcomb,
    ushort_t* __restrict__ alpha) {
    __shared__ __attribute__((aligned(16))) ushort_t wl[64 * 136];
    __shared__ __attribute__((aligned(16))) ushort_t al[64 * 136];
    int tid = threadIdx.x;
    for (int idx = tid; idx < 8192; idx += 256) {
        int r = idx >> 7, kcol = idx & 127;
        wl[r * 136 + kcol] = f2b(Wcomb[idx]);
    }
    int tb0 = blockIdx.x * 64;
    for (int idx = tid; idx < 8192; idx += 256) {
        int r = idx >> 7, kcol = idx & 127;
        al[r * 136 + kcol] = (kcol < 64)
            ? gammax[(size_t)(tb0 + r) * 64 + kcol]
            : masks[(size_t)(tb0 + r) * 64 + (kcol - 64)];
    }
    __syncthreads();
    int w = tid >> 6, lane = tid & 63, l15 = lane & 15, quad = lane >> 4;
    v4f acc[4] = {};
#pragma unroll
    for (int kt = 0; kt < 4; ++kt) {
        v8s a = *(const v8s*)(al + (w * 16 + l15) * 136 + kt * 32 + quad * 8);
#pragma unroll
        for (int nt = 0; nt < 4; ++nt) {
            v8s bfr = *(const v8s*)(wl + (nt * 16 + l15) * 136 + kt * 32 + quad * 8);
            acc[nt] = __builtin_amdgcn_mfma_f32_16x16x32_bf16(a, bfr, acc[nt], 0, 0, 0);
        }
    }
#pragma unroll
    for (int nt = 0; nt < 4; ++nt) {
        int col = nt * 16 + l15;
        float bc = bcomb[col];
#pragma unroll
        for (int j = 0; j < 4; ++j) {
            int row = w * 16 + quad * 4 + j;
            alpha[(size_t)(tb0 + row) * 64 + col] = f2b(acc[nt][j] + bc);
        }
    }
}

// ---------------------------------------------------------------------------
// k_run: persistent, 8-slot h ring, data-polling sync (bf16+1 encoding),
// producer pre-zero of slot (t+4)%8 (safe: intra-group drift <= 1 step and
// every __syncthreads drains vmcnt, so zeros are globally visible >=2 steps
// before any producer can rewrite or any consumer can poll that slot).
// [Final consolidated build = verified round-11 (total 867.9us, k_run
//  ~806-816us). Banked wins: deferred out-store (R5), SF spread over all
//  4 waves (R10), m-half Wih fold into SA (R11). Closed lines (all
//  regressed): XCD-local handoff scope, narrow/remapped h-store formats,
//  barrier-flavor changes, poll-first load ordering, LDS stride tuning.]
// ---------------------------------------------------------------------------
__global__ __launch_bounds__(256, 1) void k_run(
    const ushort_t* __restrict__ values, const ushort_t* __restrict__ masks,
    const ushort_t* __restrict__ deltas, const ushort_t* __restrict__ alpha,
    const ushort_t* __restrict__ Wih, const ushort_t* __restrict__ Whh,
    const float* __restrict__ bih, const float* __restrict__ bhh,
    const ushort_t* __restrict__ Wgh, const float* __restrict__ bgh,
    const ushort_t* __restrict__ Whist, const float* __restrict__ bhist,
    const ushort_t* __restrict__ Wfeat, const float* __restrict__ bfeat,
    ushort_t* __restrict__ hbufs, float* __restrict__ out) {
    __shared__ __attribute__((aligned(16))) ushort_t hlds[16 * 520];
    __shared__ __attribute__((aligned(16))) ushort_t inplds[16 * 136];
    __shared__ __attribute__((aligned(16))) ushort_t xclds[16 * 72];
    __shared__ __attribute__((aligned(16))) ushort_t d1b[16 * 72];
    __shared__ __attribute__((aligned(16))) float gl[4 * 16 * 36];
    __shared__ __attribute__((aligned(16))) float gam[16 * 36];

    int tid = threadIdx.x;
    int w = tid >> 6;
    int lane = tid & 63;
    int l15 = lane & 15, quad = lane >> 4;
    int wg = blockIdx.x;
    int rb = wg & 15, cb = wg >> 4;
    int b0 = rb * 16;

    // ---- persistent weight fragments ----
    v8s whhF[2][16], wihF[2][4], whisF[16], wfF[2], wghF[2] = {};
    float biasv[2];
#pragma unroll
    for (int nt2 = 0; nt2 < 2; ++nt2) {
        int hc = cb * 32 + nt2 * 16 + l15;
        int rW = w * 512 + hc;
        const ushort_t* whrow = Whh + (size_t)rW * 512;
        const ushort_t* wirow = Wih + (size_t)rW * 128;
#pragma unroll
        for (int kt = 0; kt < 16; ++kt)
            whhF[nt2][kt] = *(const v8s*)(whrow + kt * 32 + quad * 8);
#pragma unroll
        for (int kt = 0; kt < 4; ++kt)
            wihF[nt2][kt] = *(const v8s*)(wirow + kt * 32 + quad * 8);
        biasv[nt2] = bih[rW] + bhh[rW];
    }
    int colC = w * 16 + l15;
    {
        const ushort_t* hrow = Whist + (size_t)colC * 512;
#pragma unroll
        for (int kt = 0; kt < 16; ++kt)
            whisF[kt] = *(const v8s*)(hrow + kt * 32 + quad * 8);
        const ushort_t* frow = Wfeat + colC * 64;
#pragma unroll
        for (int kt = 0; kt < 2; ++kt) {
            int k0 = kt * 32 + quad * 8;
            v8s bb = *(const v8s*)(frow + k0);
#pragma unroll
            for (int j = 0; j < 8; ++j)
                if (k0 + j == colC) bb[j] = 0;   // zero diagonal
            wfF[kt] = bb;
        }
    }
    float bghv = 0.f;
    if (w < 2) {
        int gcol = cb * 32 + w * 16 + l15;
        const ushort_t* grow = Wgh + gcol * 64;
#pragma unroll
        for (int kt = 0; kt < 2; ++kt)
            wghF[kt] = *(const v8s*)(grow + kt * 32 + quad * 8);
        bghv = bgh[gcol];
    }
    float bhistv = bhist[colC];
    float bfeatv = bfeat[colC];

    int sf_row = tid >> 3, sf_c4 = (tid & 7) * 4;   // pre-zero addressing
    // SF-spread addressing: pair pr = tid>>1 owns (row, 4-col unit); this
    // thread handles cols c4 + sub*2 + {0,1}.
    int pr = tid >> 1;
    int sp_row = pr >> 3, sp_c4 = (pr & 7) * 4, sub = tid & 1;
    float c_reg2[2] = {0.f, 0.f};

    for (int t = 0; t < 256; ++t) {
        // ---- P: prefetch (no cross-wg deps) ----
        float v4r[4], m4r[4], a4r[4];
#pragma unroll
        for (int r = 0; r < 4; ++r) {
            int row = quad * 4 + r;
            size_t g = (size_t)t * 16384 + (b0 + row) * 64 + colC;
            v4r[r] = b2f(values[g]);
            m4r[r] = b2f(masks[g]);
            a4r[r] = b2f(alpha[g]);
        }
        v8s mreg = {}, dreg = {};
        if (tid < 128) {
            int row = tid >> 3, c8 = (tid & 7) * 8;
            int tn = (t < 255) ? t + 1 : 255;
            mreg = *(const v8s*)(masks + (size_t)t * 16384 + (b0 + row) * 64 + c8);
            dreg = *(const v8s*)(deltas + (size_t)tn * 16384 + (b0 + row) * 64 + c8);
        }

        // ---- S0: poll h(t) data directly; decode; stage LDS ----
        if (t == 0) {
            v8s z = {0, 0, 0, 0, 0, 0, 0, 0};
            for (int idx = tid; idx < 1040; idx += 256) ((v8s*)hlds)[idx] = z;
        } else {
            const ushort_t* hb = hbufs + (size_t)(t & 7) * 131072;
            const ull_t* hp[8];
            ull_t hv[8];
#pragma unroll
            for (int i = 0; i < 8; ++i) {
                int c = tid + 256 * i;
                int row = c >> 7, c4 = (c & 127) * 4;
                hp[i] = (const ull_t*)(hb + (b0 + row) * 512 + c4);
                hv[i] = __hip_atomic_load(hp[i], __ATOMIC_RELAXED,
                                          __HIP_MEMORY_SCOPE_AGENT);
            }
            int guard = 0;
            while (true) {
                bool any = false;
#pragma unroll
                for (int i = 0; i < 8; ++i) any |= (hv[i] == 0);
                if (!any || ++guard > (1 << 20)) break;
                __builtin_amdgcn_s_sleep(1);
#pragma unroll
                for (int i = 0; i < 8; ++i)
                    if (hv[i] == 0)
                        hv[i] = __hip_atomic_load(hp[i], __ATOMIC_RELAXED,
                                                  __HIP_MEMORY_SCOPE_AGENT);
            }
#pragma unroll
            for (int i = 0; i < 8; ++i) {
                int c = tid + 256 * i;
                int row = c >> 7, c4 = (c & 127) * 4;
                *(ull_t*)(hlds + row * 520 + c4) =
                    hv[i] - 0x0001000100010001ULL;   // decode bf16+1
            }
        }
        if (tid < 128) {
            int row = tid >> 3, c8 = (tid & 7) * 8;
            *(v8s*)(inplds + row * 136 + 64 + c8) = mreg;
            *(v8s*)(d1b + row * 72 + c8) = dreg;
        }
        __syncthreads();

        // ---- SA: xh + 2 gate chains share A-frags; m-half of Wih folded in;
        //      gamma tile; xc epilogue ----
        v4f accx = {0.f, 0.f, 0.f, 0.f};
        v4f accg0 = {0.f, 0.f, 0.f, 0.f}, accg1 = {0.f, 0.f, 0.f, 0.f};
#pragma unroll
        for (int kt = 0; kt < 16; ++kt) {
            v8s a = *(const v8s*)(hlds + l15 * 520 + kt * 32 + quad * 8);
            accx = __builtin_amdgcn_mfma_f32_16x16x32_bf16(a, whisF[kt], accx, 0, 0, 0);
            accg0 = __builtin_amdgcn_mfma_f32_16x16x32_bf16(a, whhF[0][kt], accg0, 0, 0, 0);
            accg1 = __builtin_amdgcn_mfma_f32_16x16x32_bf16(a, whhF[1][kt], accg1, 0, 0, 0);
        }
        // m-half of the gate GEMM (inplds cols 64..127, staged at S0) --
        // does NOT depend on SC; removed from the post-SC critical path.
#pragma unroll
        for (int kt = 2; kt < 4; ++kt) {
            v8s a = *(const v8s*)(inplds + l15 * 136 + kt * 32 + quad * 8);
            accg0 = __builtin_amdgcn_mfma_f32_16x16x32_bf16(a, wihF[0][kt], accg0, 0, 0, 0);
            accg1 = __builtin_amdgcn_mfma_f32_16x16x32_bf16(a, wihF[1][kt], accg1, 0, 0, 0);
        }
        if (w < 2) {
            v4f acc = {0.f, 0.f, 0.f, 0.f};
#pragma unroll
            for (int kt = 0; kt < 2; ++kt) {
                v8s a = *(const v8s*)(d1b + l15 * 72 + kt * 32 + quad * 8);
                acc = __builtin_amdgcn_mfma_f32_16x16x32_bf16(a, wghF[kt], acc, 0, 0, 0);
            }
#pragma unroll
            for (int r = 0; r < 4; ++r) {
                float s = acc[r] + bghv;
                gam[(quad * 4 + r) * 36 + w * 16 + l15] = (s > 0.f) ? __expf(-s) : 1.f;
            }
        }
        float xh4[4];
#pragma unroll
        for (int r = 0; r < 4; ++r) {
            float xh = accx[r] + bhistv;
            float xc = m4r[r] * v4r[r] + (1.f - m4r[r]) * xh;
            xclds[(quad * 4 + r) * 72 + colC] = f2b(xc);
            xh4[r] = xh;
        }
        __syncthreads();

        // ---- SC: z_h MFMA; c_h/c_c epilogue in C-layout; cc kept in regs ----
        float cc4[4];
        {
            v4f accz = {0.f, 0.f, 0.f, 0.f};
#pragma unroll
            for (int kt = 0; kt < 2; ++kt) {
                v8s a = *(const v8s*)(xclds + l15 * 72 + kt * 32 + quad * 8);
                accz = __builtin_amdgcn_mfma_f32_16x16x32_bf16(a, wfF[kt], accz, 0, 0, 0);
            }
#pragma unroll
            for (int r = 0; r < 4; ++r) {
                float zh = accz[r] + bfeatv;
                float ch = a4r[r] * zh + (1.f - a4r[r]) * xh4[r];
                float cc = m4r[r] * v4r[r] + (1.f - m4r[r]) * ch;
                int row = quad * 4 + r;
                inplds[row * 136 + colC] = f2b(cc);
                cc4[r] = cc;   // out-store deferred to step tail
            }
        }
        __syncthreads();

        // ---- SE: gates Wih cc-half only (kt=0,1); gate planes ----
#pragma unroll
        for (int nt2 = 0; nt2 < 2; ++nt2) {
            v4f acc = (nt2 == 0) ? accg0 : accg1;
#pragma unroll
            for (int kt = 0; kt < 2; ++kt) {
                v8s a = *(const v8s*)(inplds + l15 * 136 + kt * 32 + quad * 8);
                acc = __builtin_amdgcn_mfma_f32_16x16x32_bf16(a, wihF[nt2][kt], acc, 0, 0, 0);
            }
#pragma unroll
            for (int r = 0; r < 4; ++r)
                gl[w * 576 + (quad * 4 + r) * 36 + nt2 * 16 + l15] = acc[r] + biasv[nt2];
        }
        __syncthreads();

        // ---- SF: LSTM spread over ALL 256 threads (2 cols each);
        //      shfl-merge to the identical 8B encoded store ----
        {
            uint_t myu = 0;
#pragma unroll
            for (int jj = 0; jj < 2; ++jj) {
                int hcl = sp_c4 + sub * 2 + jj;
                float gi = gl[0 * 576 + sp_row * 36 + hcl];
                float gf = gl[1 * 576 + sp_row * 36 + hcl];
                float gg = gl[2 * 576 + sp_row * 36 + hcl];
                float go = gl[3 * 576 + sp_row * 36 + hcl];
                float si = 1.f / (1.f + __expf(-gi));
                float sf = 1.f / (1.f + __expf(-gf));
                float tg = 1.f - 2.f / (__expf(2.f * gg) + 1.f);
                float so = 1.f / (1.f + __expf(-go));
                float cn = sf * c_reg2[jj] + si * tg;
                c_reg2[jj] = cn;
                float hn = so * (1.f - 2.f / (__expf(2.f * cn) + 1.f));
                float g = gam[sp_row * 36 + hcl];
                myu |= (uint_t)(ushort_t)(f2b(hn * g) + 1) << (16 * jj);
            }
            uint_t pu = __shfl_xor(myu, 1);
            if (sub == 0 && t < 255) {
                ull_t outv = (ull_t)myu | ((ull_t)pu << 32);
                ushort_t* hnx = hbufs + (size_t)((t + 1) & 7) * 131072;
                size_t myoff = (size_t)(b0 + sp_row) * 512 + cb * 32 + sp_c4;
                __hip_atomic_store((ull_t*)(hnx + myoff), outv,
                                   __ATOMIC_RELAXED, __HIP_MEMORY_SCOPE_AGENT);
            }
        }
        // ---- pre-zero slot (t+4)%8 (8B per thread, tid<128; unchanged) ----
        if (tid < 128 && t + 4 < 256) {
            ushort_t* hz = hbufs + (size_t)((t + 4) & 7) * 131072;
            size_t myoff = (size_t)(b0 + sf_row) * 512 + cb * 32 + sf_c4;
            __hip_atomic_store((ull_t*)(hz + myoff), 0ULL,
                               __ATOMIC_RELAXED, __HIP_MEMORY_SCOPE_AGENT);
        }
        // ---- deferred out store (issued after h publish; drains with it) ----
        if (cb == 0) {
#pragma unroll
            for (int r = 0; r < 4; ++r) {
                int row = quad * 4 + r;
                out[(size_t)(b0 + row) * 16384 + t * 64 + colC] = cc4[r];
            }
        }
        __syncthreads();   // drains vmcnt: protects LDS reuse + publishes h/zeros
    }
}

extern "C" void kernel_launch(void* const* d_in, const int* in_sizes, int n_in,
                              void* d_out, int out_size, void* d_ws, size_t ws_size,
                              hipStream_t stream) {
    const float* data  = (const float*)d_in[0];
    const float* Wih   = (const float*)d_in[1];
    const float* Whh   = (const float*)d_in[2];
    const float* bih   = (const float*)d_in[3];
    const float* bhh   = (const float*)d_in[4];
    const float* Wgh   = (const float*)d_in[5];
    const float* bgh   = (const float*)d_in[6];
    const float* Wgx   = (const float*)d_in[7];
    const float* bgx   = (const float*)d_in[8];
    const float* Whist = (const float*)d_in[9];
    const float* bhist = (const float*)d_in[10];
    const float* Wfeat = (const float*)d_in[11];
    const float* bfeat = (const float*)d_in[12];
    const float* Wcomb = (const float*)d_in[13];
    const float* bcomb = (const float*)d_in[14];
    float* out = (float*)d_out;

    char* ws = (char*)d_ws;
    const size_t NTBC = 256UL * 256 * 64;
    ushort_t* valuesb = (ushort_t*)ws; ws += NTBC * 2;
    ushort_t* masksp  = (ushort_t*)ws; ws += NTBC * 2;
    ushort_t* deltasp = (ushort_t*)ws; ws += NTBC * 2;
    ushort_t* gammax  = (ushort_t*)ws; ws += NTBC * 2;
    ushort_t* alphap  = (ushort_t*)ws; ws += NTBC * 2;
    ushort_t* Wih_b   = (ushort_t*)ws; ws += 2048UL * 128 * 2;
    ushort_t* Whh_b   = (ushort_t*)ws; ws += 2048UL * 512 * 2;
    ushort_t* Wgh_b   = (ushort_t*)ws; ws += 512UL * 64 * 2;
    ushort_t* Whist_b = (ushort_t*)ws; ws += 64UL * 512 * 2;
    ushort_t* Wfeat_b = (ushort_t*)ws; ws += 64UL * 64 * 2;
    ushort_t* hbufs   = (ushort_t*)ws; ws += 8UL * 131072 * 2;  // 2 MB ring
    // total ~44.6 MiB

    k_prep<<<1924, 256, 0, stream>>>(Wih, Whh, Wgh, Whist, Wfeat,
                                     Wih_b, Whh_b, Wgh_b, Whist_b, Wfeat_b,
                                     (ull_t*)hbufs,
                                     data, Wgx, bgx,
                                     valuesb, masksp, deltasp, gammax);
    k_alpha<<<1024, 256, 0, stream>>>(gammax, masksp, Wcomb, bcomb, alphap);
    k_run<<<256, 256, 0, stream>>>(valuesb, masksp, deltasp, alphap,
                                   Wih_b, Whh_b, bih, bhh,
                                   Wgh_b, bgh, Whist_b, bhist,
                                   Wfeat_b, bfeat, hbufs, out);
}